// Round 1
// baseline (93.800 us; speedup 1.0000x reference)
//
#include <hip/hip_runtime.h>

#define HH 512
#define WW 512
#define NB 16
#define RPB 8
#define NCHUNK (HH / RPB)      // 64 row-chunks per batch item
#define NBLOCKS (NB * NCHUNK)  // 1024 partials

// One block per (batch, 8-row chunk). Uniform branch per block (dx is per-batch).
__global__ __launch_bounds__(256) void mbfs_main(
    const float* __restrict__ grid,
    const float* __restrict__ gt,
    const float* __restrict__ gd,
    const float* __restrict__ mask,
    float* __restrict__ partials)
{
    const int b     = blockIdx.y;
    const int chunk = blockIdx.x;
    const int row0  = chunk * RPB;

    const float dx   = -8.0f * gt[2 * b + 0];
    const float dy   =  8.0f * gt[2 * b + 1];
    const float symx = gd[2 * b + 0];
    const float symy = gd[2 * b + 1];

    const float dy1f = floorf(dy);
    const float dx1f = floorf(dx);
    const int dy1 = (int)dy1f;
    const int dx1 = (int)dx1f;
    const int dy2 = dy1 + 1;
    const int dx2 = dx1 + 1;
    const float wc1 = (dx1f + 1.0f) - dx;
    const float wc2 = dx - dx1f;
    const float wr1 = (dy1f + 1.0f) - dy;
    const float wr2 = dy - dy1f;

    const float* g0 = grid + (size_t)b * 2 * HH * WW;
    const float* g1 = g0 + HH * WW;
    const float* mk = mask + (size_t)b * HH * WW;

    const int imax = HH - dy2;   // rows valid for i < imax (both branches)
    float acc = 0.0f;
    float cnt;

    if (dx > 0.0f) {
        // delta_p = g - bilinear(g; i+dy, j+dx); weights sum to 1.
        // Valid region guarantees all indices in range (dy1,dx1 >= 0).
        const int jmax = WW - dx2;
        cnt = (float)imax * (float)jmax;
        const int rend = min(row0 + RPB, imax);
        for (int i = row0; i < rend; ++i) {
            const float* gc0 = g0 + i * WW;
            const float* gc1 = g1 + i * WW;
            const float* ga0 = g0 + (i + dy1) * WW;
            const float* gb0 = g0 + (i + dy2) * WW;
            const float* ga1 = g1 + (i + dy1) * WW;
            const float* gb1 = g1 + (i + dy2) * WW;
            const float* mr  = mk + i * WW;
            for (int j = threadIdx.x; j < jmax; j += 256) {
                float s0 = wc1 * (wr1 * ga0[j + dx1] + wr2 * gb0[j + dx1])
                         + wc2 * (wr1 * ga0[j + dx2] + wr2 * gb0[j + dx2]);
                float s1 = wc1 * (wr1 * ga1[j + dx1] + wr2 * gb1[j + dx1])
                         + wc2 * (wr1 * ga1[j + dx2] + wr2 * gb1[j + dx2]);
                float d0 = gc0[j] - s0;
                float d1 = gc1[j] - s1;
                float e  = d0 * symy + d1 * symx;
                acc += mr[j] * e * e;
            }
        }
    } else {
        // Negative branch. Using wr1+wr2 = wc1+wc2 = 1 and j+1-dx2 == j-dx1:
        // delta_n = wc1*G(i+dy2, j) + wc2*G(i+dy2, j+1)
        //         - wr1*G(i+1, j-dx1) - wr2*G(i, j-dx1)
        // Valid region (j < W+dx1, dx1 <= 0) keeps all indices in range
        // except j+1 when dx1 == 0 -> clip jp1.
        const int jmax = WW + dx1;
        cnt = (float)imax * (float)jmax;
        const int rend = min(row0 + RPB, imax);
        for (int i = row0; i < rend; ++i) {
            const float* r2p0  = g0 + (i + dy2) * WW;
            const float* r2p1  = g1 + (i + dy2) * WW;
            const float* rip0  = g0 + i * WW;
            const float* rip1  = g1 + i * WW;
            const float* ri1p0 = g0 + (i + 1) * WW;
            const float* ri1p1 = g1 + (i + 1) * WW;
            const float* mr    = mk + (i + dy2) * WW;
            for (int j = threadIdx.x; j < jmax; j += 256) {
                int jp1 = j + 1; if (jp1 > WW - 1) jp1 = WW - 1;
                int jm  = j - dx1;
                float d0 = wc1 * r2p0[j] + wc2 * r2p0[jp1]
                         - wr1 * ri1p0[jm] - wr2 * rip0[jm];
                float d1 = wc1 * r2p1[j] + wc2 * r2p1[jp1]
                         - wr1 * ri1p1[jm] - wr2 * rip1[jm];
                float e  = d0 * symy + d1 * symx;
                acc += mr[jm] * e * e;
            }
        }
    }

    // Block reduction: wave64 shuffle, then LDS across the 4 waves.
    #pragma unroll
    for (int off = 32; off > 0; off >>= 1)
        acc += __shfl_down(acc, off, 64);
    __shared__ float part[4];
    const int lane = threadIdx.x & 63;
    const int wv   = threadIdx.x >> 6;
    if (lane == 0) part[wv] = acc;
    __syncthreads();
    if (threadIdx.x == 0) {
        float s = part[0] + part[1] + part[2] + part[3];
        // Pre-scale: per-item mean over cnt, then mean over NB items.
        partials[b * NCHUNK + chunk] = s / (cnt * (float)NB);
    }
}

__global__ __launch_bounds__(256) void mbfs_reduce(
    const float* __restrict__ partials, float* __restrict__ out)
{
    float v = 0.0f;
    for (int idx = threadIdx.x; idx < NBLOCKS; idx += 256) v += partials[idx];
    #pragma unroll
    for (int off = 32; off > 0; off >>= 1)
        v += __shfl_down(v, off, 64);
    __shared__ float part[4];
    const int lane = threadIdx.x & 63;
    const int wv   = threadIdx.x >> 6;
    if (lane == 0) part[wv] = v;
    __syncthreads();
    if (threadIdx.x == 0) out[0] = part[0] + part[1] + part[2] + part[3];
}

extern "C" void kernel_launch(void* const* d_in, const int* in_sizes, int n_in,
                              void* d_out, int out_size, void* d_ws, size_t ws_size,
                              hipStream_t stream) {
    const float* grid_p = (const float*)d_in[0];  // (16, 2, 512, 512)
    const float* gt_p   = (const float*)d_in[1];  // (16, 2)
    const float* gd_p   = (const float*)d_in[2];  // (16, 2)
    const float* mask_p = (const float*)d_in[3];  // (16, 512, 512)
    float* out_p = (float*)d_out;
    float* ws_p  = (float*)d_ws;                  // NBLOCKS floats of partials

    dim3 g(NCHUNK, NB);
    mbfs_main<<<g, 256, 0, stream>>>(grid_p, gt_p, gd_p, mask_p, ws_p);
    mbfs_reduce<<<1, 256, 0, stream>>>(ws_p, out_p);
}